// Round 14
// baseline (322.905 us; speedup 1.0000x reference)
//
#include <hip/hip_runtime.h>
#include <hip/hip_fp16.h>
#include <math.h>

// 2-layer GAT. N=50000, E=800000 (+N self loops), F=128, H=8, C=32, NCLS=16.
// R14: (a) CSR build reverted to GLOBAL-ATOMIC hist/scatter (R5 proved atomics
// cheap; the LDS-histogram machinery's partial array = ~50MB extra traffic +
// fixed loops was the real cost). deg hist -> scan(+cursor, under gemm1) ->
// scatter(atomic cursor + block prefix) + rowfin. partial[] deleted.
// (b) agg1: 128-thr blocks, 2 waves per dst (even/odd edges, LDS combine,
// same-degree waves -> no barrier skew). Tests MLP vs HBM-random bound.
//   K1 hist+wprep | K2 scan+gemm1 | K3 scatter+rowfin | K4 agg1 | K5 gemm2 | K6 agg2

typedef _Float16 f16x8 __attribute__((ext_vector_type(8)));
typedef _Float16 f16x4 __attribute__((ext_vector_type(4)));
typedef float    f32x4 __attribute__((ext_vector_type(4)));

__device__ __forceinline__ float lrelu(float v){ return v > 0.f ? v : 0.2f*v; }

// ---------------- K1: global-atomic hist + weight prep ----------------
__global__ __launch_bounds__(256) void k_histW(const int* __restrict__ dstv,
    int* __restrict__ deg, int E, int Etot, int HB,
    const float* __restrict__ W1, _Float16* __restrict__ W1t,
    const float* __restrict__ W2, _Float16* __restrict__ W2t)
{
  int b = blockIdx.x, t = threadIdx.x;
  if (b >= HB){
    int b2 = b - HB;
    if (b2 < 128){
      W1t[t*128 + b2] = (_Float16)W1[b2*256 + t];
    } else {
      for (int i=t; i<4096; i+=256){ int k=i&255, j=i>>8; W2t[j*256+k] = (_Float16)W2[k*16+j]; }
    }
    return;
  }
  int e = b*256 + t;
  if (e >= Etot) return;
  int d = (e < E) ? dstv[e] : (e - E);
  atomicAdd(&deg[d], 1);
}

// ---------------- K2: scan (blocks 0..SB-1, writes rowptr+cursor+bsum) + GEMM1 ----------------
__global__ __launch_bounds__(256) void k_g1scan(const float* __restrict__ x,
    const _Float16* __restrict__ W1t, const float* __restrict__ as1,
    const float* __restrict__ ad1, _Float16* __restrict__ h1,
    float* __restrict__ a_src1, float* __restrict__ a_dst1,
    const int* __restrict__ deg, int* __restrict__ rowptr, int* __restrict__ cursor,
    int* __restrict__ bsum, int N, int SB)
{
  __shared__ char smem[33792];
  int t = threadIdx.x;
  int b = blockIdx.x;

  if (b < SB){
    int* lds = (int*)smem;
    int base = b*1024 + t*4;
    int v0 = (base+0<N)?deg[base+0]:0;
    int v1 = (base+1<N)?deg[base+1]:0;
    int v2 = (base+2<N)?deg[base+2]:0;
    int v3 = (base+3<N)?deg[base+3]:0;
    int tot = v0+v1+v2+v3;
    lds[t] = tot; __syncthreads();
    for (int off=1; off<256; off<<=1){
      int add = (t>=off)?lds[t-off]:0;
      __syncthreads();
      lds[t] += add;
      __syncthreads();
    }
    int excl = lds[t] - tot;
    if (t==255) bsum[b] = lds[t];
    int run = excl;
    if (base+0<N){ rowptr[base+0]=run; cursor[base+0]=run; run+=v0; }
    if (base+1<N){ rowptr[base+1]=run; cursor[base+1]=run; run+=v1; }
    if (base+2<N){ rowptr[base+2]=run; cursor[base+2]=run; run+=v2; }
    if (base+3<N){ rowptr[base+3]=run; cursor[base+3]=run; }
    return;
  }

  // ---- GEMM1 (MFMA): h1 = x @ W1 -> fp16, + a_src1/a_dst1 ----
  _Float16* As = (_Float16*)smem;           // [64 rows][136 halves] (272 B stride)
  int n0 = (b - SB)*64;

  #pragma unroll
  for (int it=0; it<8; ++it){
    int c = it*256 + t;
    int row = c >> 5;
    int c4  = c & 31;
    int gr = n0 + row; if (gr > N-1) gr = N-1;
    float4 v = *(const float4*)(x + (size_t)gr*128 + c4*4);
    _Float16* dp = As + row*136 + c4*4;
    dp[0]=(_Float16)v.x; dp[1]=(_Float16)v.y; dp[2]=(_Float16)v.z; dp[3]=(_Float16)v.w;
  }
  __syncthreads();

  int wv = t>>6, lane = t&63;
  int m = lane&15, q = lane>>4;
  int r0w = wv*16;

  f16x8 afr[4];
  #pragma unroll
  for (int ks=0; ks<4; ++ks)
    afr[ks] = *(const f16x8*)((const char*)As + (r0w+m)*272 + ks*64 + q*16);

  f32x4 acc[16];
  #pragma unroll
  for (int ct=0; ct<16; ++ct) acc[ct] = (f32x4){0.f,0.f,0.f,0.f};

  const char* bbase = (const char*)W1t;
  #pragma unroll
  for (int ct=0; ct<16; ++ct){
    const char* bp = bbase + (ct*16 + m)*256 + q*16;
    f16x8 b0 = *(const f16x8*)(bp);
    f16x8 b1 = *(const f16x8*)(bp+64);
    f16x8 b2 = *(const f16x8*)(bp+128);
    f16x8 b3 = *(const f16x8*)(bp+192);
    acc[ct] = __builtin_amdgcn_mfma_f32_16x16x32_f16(afr[0], b0, acc[ct],0,0,0);
    acc[ct] = __builtin_amdgcn_mfma_f32_16x16x32_f16(afr[1], b1, acc[ct],0,0,0);
    acc[ct] = __builtin_amdgcn_mfma_f32_16x16x32_f16(afr[2], b2, acc[ct],0,0,0);
    acc[ct] = __builtin_amdgcn_mfma_f32_16x16x32_f16(afr[3], b3, acc[ct],0,0,0);
  }
  __syncthreads();

  _Float16* Hs = (_Float16*)smem;           // [64][264] halves, 528B stride
  #pragma unroll
  for (int ct=0; ct<16; ++ct){
    #pragma unroll
    for (int r=0; r<4; ++r)
      Hs[(size_t)(r0w + q*4 + r)*264 + ct*16 + m] = (_Float16)acc[ct][r];
  }
  __syncthreads();

  for (int r=0; r<16; ++r){
    int grow = n0 + r0w + r;
    if (grow < N){
      uint2 v = *(const uint2*)((const char*)Hs + (size_t)(r0w+r)*528 + lane*8);
      *(uint2*)((char*)h1 + (size_t)grow*512 + lane*8) = v;
    }
  }

  #pragma unroll
  for (int p=t; p<512; p+=256){
    int row = p>>3, hd = p&7;
    int grow = n0 + row;
    if (grow < N){
      const _Float16* hr = Hs + (size_t)row*264 + hd*32;
      float sa=0.f, sd=0.f;
      #pragma unroll
      for (int c=0; c<32; ++c){
        float hv = (float)hr[c];
        sa += hv * as1[hd*32+c];
        sd += hv * ad1[hd*32+c];
      }
      a_src1[(size_t)grow*8+hd] = sa;
      a_dst1[(size_t)grow*8+hd] = sd;
    }
  }
}

// ---------------- K3: scatter (global atomic cursor + block prefix) + rowfin ----------------
__global__ __launch_bounds__(256) void k_scatter3(const int* __restrict__ srcv,
    const int* __restrict__ dstv, const int* __restrict__ rowptr,
    int* __restrict__ cursor, const int* __restrict__ bsum,
    int* __restrict__ csr_src, int* __restrict__ rowfin,
    int E, int Etot, int SB, int N)
{
  __shared__ int bpre[64];
  int b = blockIdx.x, t = threadIdx.x;
  if (t < SB){ int run=0; for (int j=0;j<t;++j) run += bsum[j]; bpre[t] = run; }
  __syncthreads();

  // finalize rowptr into rowfin (blocks 0..SB-1)
  if (b < SB){
    int pref = bpre[b];
    int i = b*1024 + t*4;
    if (i+0 < N) rowfin[i+0] = rowptr[i+0] + pref;
    if (i+1 < N) rowfin[i+1] = rowptr[i+1] + pref;
    if (i+2 < N) rowfin[i+2] = rowptr[i+2] + pref;
    if (i+3 < N) rowfin[i+3] = rowptr[i+3] + pref;
    if (b==0 && t==0) rowfin[N] = Etot;
  }

  int e = b*256 + t;
  if (e >= Etot) return;
  int s, d;
  if (e < E){ s = srcv[e]; d = dstv[e]; } else { s = e - E; d = s; }
  int lpos = atomicAdd(&cursor[d], 1);           // local (pre-prefix) slot
  csr_src[lpos + bpre[d>>10]] = s;
}

// ---------------- K4: Layer-1 aggregation: 2 waves per dst (even/odd edges) ----------------
__global__ __launch_bounds__(128) void k_agg1(const __half* __restrict__ h1,
    const float* __restrict__ a_src1, const float* __restrict__ a_dst1,
    const int* __restrict__ rowfin, const int* __restrict__ csr_src,
    const float* __restrict__ bias1, _Float16* __restrict__ h2f, int N)
{
  __shared__ float Xa[64][4];
  __shared__ float Xw[64];
  int dst = blockIdx.x;
  int t = threadIdx.x;
  int wv = t >> 6;              // 0 or 1 (edge parity)
  int lane = t & 63;
  int head = lane >> 3;
  float ad = a_dst1[(size_t)dst*8 + head];
  int beg = rowfin[dst], end = rowfin[dst+1];
  float4 acc = make_float4(0.f,0.f,0.f,0.f);
  float wsum = 0.f;
  int i = beg + wv;
  for (; i + 6 < end; i += 8){   // 4 edges per wave per iter (stride 2)
    int s0=csr_src[i], s1=csr_src[i+2], s2=csr_src[i+4], s3=csr_src[i+6];
    float e0=a_src1[(size_t)s0*8+head], e1=a_src1[(size_t)s1*8+head];
    float e2=a_src1[(size_t)s2*8+head], e3=a_src1[(size_t)s3*8+head];
    uint2 p0 = *(const uint2*)((const char*)h1 + (size_t)s0*512 + lane*8);
    uint2 p1 = *(const uint2*)((const char*)h1 + (size_t)s1*512 + lane*8);
    uint2 p2 = *(const uint2*)((const char*)h1 + (size_t)s2*512 + lane*8);
    uint2 p3 = *(const uint2*)((const char*)h1 + (size_t)s3*512 + lane*8);
    float w0=__expf(lrelu(e0+ad)), w1=__expf(lrelu(e1+ad));
    float w2=__expf(lrelu(e2+ad)), w3=__expf(lrelu(e3+ad));
    wsum += (w0+w1)+(w2+w3);
    const __half2* q0=(const __half2*)&p0; const __half2* q1=(const __half2*)&p1;
    const __half2* q2=(const __half2*)&p2; const __half2* q3=(const __half2*)&p3;
    float2 a0=__half22float2(q0[0]), b0=__half22float2(q0[1]);
    float2 a1=__half22float2(q1[0]), b1=__half22float2(q1[1]);
    float2 a2=__half22float2(q2[0]), b2=__half22float2(q2[1]);
    float2 a3=__half22float2(q3[0]), b3=__half22float2(q3[1]);
    acc.x += w0*a0.x + w1*a1.x + w2*a2.x + w3*a3.x;
    acc.y += w0*a0.y + w1*a1.y + w2*a2.y + w3*a3.y;
    acc.z += w0*b0.x + w1*b1.x + w2*b2.x + w3*b3.x;
    acc.w += w0*b0.y + w1*b1.y + w2*b2.y + w3*b3.y;
  }
  for (; i < end; i += 2){
    int s = csr_src[i];
    float w = __expf(lrelu(a_src1[(size_t)s*8+head] + ad));
    wsum += w;
    uint2 p = *(const uint2*)((const char*)h1 + (size_t)s*512 + lane*8);
    const __half2* qq=(const __half2*)&p;
    float2 f0=__half22float2(qq[0]), f1=__half22float2(qq[1]);
    acc.x += w*f0.x; acc.y += w*f0.y; acc.z += w*f1.x; acc.w += w*f1.y;
  }
  // combine the two waves (same dst, same trip count -> no skew)
  if (wv == 1){
    Xa[lane][0]=acc.x; Xa[lane][1]=acc.y; Xa[lane][2]=acc.z; Xa[lane][3]=acc.w;
    Xw[lane]=wsum;
  }
  __syncthreads();
  if (wv == 0){
    acc.x += Xa[lane][0]; acc.y += Xa[lane][1];
    acc.z += Xa[lane][2]; acc.w += Xa[lane][3];
    wsum  += Xw[lane];
    float dinv = 1.f/(wsum + 1e-16f);
    const float4 bv = *(const float4*)(bias1 + lane*4);
    float4 o;
    o.x = acc.x*dinv + bv.x;
    o.y = acc.y*dinv + bv.y;
    o.z = acc.z*dinv + bv.z;
    o.w = acc.w*dinv + bv.w;
    o.x = o.x > 0.f ? o.x : __expf(o.x)-1.f;
    o.y = o.y > 0.f ? o.y : __expf(o.y)-1.f;
    o.z = o.z > 0.f ? o.z : __expf(o.z)-1.f;
    o.w = o.w > 0.f ? o.w : __expf(o.w)-1.f;
    f16x4 ov = { (_Float16)o.x, (_Float16)o.y, (_Float16)o.z, (_Float16)o.w };
    *(f16x4*)(h2f + (size_t)dst*256 + lane*4) = ov;
  }
}

// ---------------- K5: GEMM2 (MFMA): hb(fp16) = h2f @ W2, + a_src2/a_dst2 ----------------
__global__ __launch_bounds__(256) void k_gemm2(const _Float16* __restrict__ h2f,
    const _Float16* __restrict__ W2t, const float* __restrict__ as2, const float* __restrict__ ad2,
    _Float16* __restrict__ hbh, float* __restrict__ a_src2, float* __restrict__ a_dst2, int N)
{
  int t = threadIdx.x, wv = t>>6, lane = t&63;
  int col = lane&15, q = lane>>4;
  int n0 = blockIdx.x*64 + wv*16;
  int am = n0 + col; if (am > N-1) am = N-1;

  const _Float16* arow = h2f + (size_t)am*256 + q*8;
  const _Float16* brow = W2t + (size_t)col*256 + q*8;
  f32x4 acc = (f32x4){0.f,0.f,0.f,0.f};
  #pragma unroll
  for (int ks=0; ks<8; ++ks){
    f16x8 a = *(const f16x8*)(arow + ks*32);
    f16x8 b = *(const f16x8*)(brow + ks*32);
    acc = __builtin_amdgcn_mfma_f32_16x16x32_f16(a, b, acc, 0,0,0);
  }

  float vs = as2[col], vd = ad2[col];
  #pragma unroll
  for (int r=0; r<4; ++r){
    int n = n0 + q*4 + r;
    float v = acc[r];
    float pa = v*vs, pd = v*vd;
    #pragma unroll
    for (int msk=8; msk>=1; msk>>=1){ pa += __shfl_xor(pa,msk); pd += __shfl_xor(pd,msk); }
    if (n < N){
      hbh[(size_t)n*16 + col] = (_Float16)v;
      if (col==0){ a_src2[n] = pa; a_dst2[n] = pd; }
    }
  }
}

// ---------------- K6: Layer-2 aggregation: wave per dst, 4 edge-groups x 16 ch ----------------
__global__ __launch_bounds__(256) void k_agg2(const __half* __restrict__ hbh,
    const float* __restrict__ a_src2, const float* __restrict__ a_dst2,
    const int* __restrict__ rowfin, const int* __restrict__ csr_src,
    const float* __restrict__ bias2, float* __restrict__ out, int N)
{
  int wave = (blockIdx.x*blockDim.x + threadIdx.x) >> 6;
  if (wave >= N) return;
  int lane = threadIdx.x & 63;
  int eg   = lane >> 4;
  int ch   = lane & 15;
  float ad = a_dst2[wave];
  int beg = rowfin[wave], end = rowfin[wave+1];
  float acc = 0.f, wsum = 0.f;
  int i = beg + eg;
  for (; i+4 < end; i+=8){
    int s0 = csr_src[i], s1 = csr_src[i+4];
    float e0 = a_src2[s0], e1 = a_src2[s1];
    float h0 = __half2float(hbh[(size_t)s0*16 + ch]);
    float h1v = __half2float(hbh[(size_t)s1*16 + ch]);
    float w0 = __expf(lrelu(e0 + ad)), w1 = __expf(lrelu(e1 + ad));
    wsum += w0 + w1;
    acc += w0*h0 + w1*h1v;
  }
  for (; i<end; i+=4){
    int s = csr_src[i];
    float w = __expf(lrelu(a_src2[s] + ad));
    wsum += w;
    acc += w * __half2float(hbh[(size_t)s*16 + ch]);
  }
  acc  += __shfl_xor(acc, 16);  acc  += __shfl_xor(acc, 32);
  wsum += __shfl_xor(wsum, 16); wsum += __shfl_xor(wsum, 32);
  if (eg == 0)
    out[(size_t)wave*16 + ch] = acc/(wsum + 1e-16f) + bias2[ch];
}

extern "C" void kernel_launch(void* const* d_in, const int* in_sizes, int n_in,
                              void* d_out, int out_size, void* d_ws, size_t ws_size,
                              hipStream_t stream)
{
  const float* x   = (const float*)d_in[0];
  const int*   ei  = (const int*)  d_in[1];
  const float* W1  = (const float*)d_in[2];
  const float* as1 = (const float*)d_in[3];
  const float* ad1 = (const float*)d_in[4];
  const float* b1  = (const float*)d_in[5];
  const float* W2  = (const float*)d_in[6];
  const float* as2 = (const float*)d_in[7];
  const float* ad2 = (const float*)d_in[8];
  const float* b2  = (const float*)d_in[9];
  float* out = (float*)d_out;

  const int N    = in_sizes[0] / 128;       // 50000
  const int E    = in_sizes[1] / 2;         // 800000
  const int Etot = E + N;
  const int* srcv = ei;
  const int* dstv = ei + E;
  const int HB    = (Etot + 255) / 256;     // hist/scatter edge blocks (3321)
  const int SB    = (N + 1023) / 1024;      // 49 scan blocks
  const int TN    = (N + 63) / 64;          // 782 gemm1 tiles

  char* p = (char*)d_ws;
  auto alloc = [&](size_t bytes)->void* {
    void* r = (void*)p;
    p += (bytes + 255) & ~((size_t)255);
    return r;
  };
  _Float16* h1   = (_Float16*)alloc((size_t)N*256*sizeof(_Float16));   // node-major [N][256]
  _Float16* W1t  = (_Float16*)alloc((size_t)256*128*sizeof(_Float16));
  _Float16* h2f  = (_Float16*)alloc((size_t)N*256*sizeof(_Float16));
  _Float16* W2t  = (_Float16*)alloc((size_t)16*256*sizeof(_Float16));
  _Float16* hbh  = (_Float16*)alloc((size_t)N*16*sizeof(_Float16));
  float* a_src1  = (float*)alloc((size_t)N*8*sizeof(float));
  float* a_dst1  = (float*)alloc((size_t)N*8*sizeof(float));
  float* a_src2  = (float*)alloc((size_t)N*sizeof(float));
  float* a_dst2  = (float*)alloc((size_t)N*sizeof(float));
  int*   deg     = (int*)alloc((size_t)N*sizeof(int));
  int*   rowptr  = (int*)alloc((size_t)(N+1)*sizeof(int));
  int*   cursor  = (int*)alloc((size_t)N*sizeof(int));
  int*   rowfin  = (int*)alloc((size_t)(N+1)*sizeof(int));
  int*   bsum    = (int*)alloc(256*sizeof(int));
  int*   csr_src = (int*)alloc((size_t)Etot*sizeof(int));

  hipMemsetAsync(deg, 0, (size_t)N*sizeof(int), stream);
  // K1: global-atomic histogram + weight prep
  k_histW<<<dim3(HB+129), dim3(256), 0, stream>>>(dstv, deg, E, Etot, HB,
                                                  W1, W1t, W2, W2t);
  // K2: scan (blocks 0..SB-1: rowptr+cursor+bsum) + gemm1 (blocks SB..)
  k_g1scan<<<dim3(SB + TN), dim3(256), 0, stream>>>(x, W1t, as1, ad1, h1,
      a_src1, a_dst1, deg, rowptr, cursor, bsum, N, SB);
  // K3: scatter (atomic cursor + block prefix) + rowfin finalize
  k_scatter3<<<dim3(HB), dim3(256), 0, stream>>>(srcv, dstv, rowptr, cursor, bsum,
      csr_src, rowfin, E, Etot, SB, N);
  // K4: agg1 (2 waves per dst)
  k_agg1<<<dim3(N), dim3(128), 0, stream>>>((const __half*)h1, a_src1, a_dst1,
      rowfin, csr_src, b1, h2f, N);
  // K5: gemm2 (fp16 hb)
  k_gemm2<<<dim3((N + 63)/64), dim3(256), 0, stream>>>(h2f, W2t, as2, ad2, hbh, a_src2, a_dst2, N);
  // K6: agg2
  k_agg2<<<dim3((N + 3)/4), dim3(256), 0, stream>>>((const __half*)hbh, a_src2, a_dst2,
      rowfin, csr_src, b2, out, N);
}

// Round 15
// 273.484 us; speedup vs baseline: 1.1807x; 1.1807x over previous
//
#include <hip/hip_runtime.h>
#include <hip/hip_fp16.h>
#include <math.h>

// 2-layer GAT. N=50000, E=800000 (+N self loops), F=128, H=8, C=32, NCLS=16.
// R15: full revert to R13 (best, 269.8us; R14's global-atomic CSR cost +53us,
// and proved agg1 is HBM-random-bound at ~70us -- its floor). DIAGNOSTIC:
// agg1 split into two half-grid launches (~35us each) so the true second-
// largest kernel surfaces in the rocprof top-5 and can be targeted next.
//   K1 histW | K2 scanAB+gemm1 | K3 scatter3+rowfin | K4a/K4b agg1 halves
//   | K5 gemm2 | K6 agg2

#define NC    128          // edge chunks
#define NBK   256          // hist/scatter blocks = NC * 2 halves
#define NBINS 50000
#define HBINS 25000        // bins per half
#define NWH   12500        // packed u32 words per half (2 bins each)

typedef _Float16 f16x8 __attribute__((ext_vector_type(8)));
typedef _Float16 f16x4 __attribute__((ext_vector_type(4)));
typedef float    f32x4 __attribute__((ext_vector_type(4)));

__device__ __forceinline__ float lrelu(float v){ return v > 0.f ? v : 0.2f*v; }

// ---------------- K1: hist (packed u16, chunk x half) + weight prep ----------------
__global__ __launch_bounds__(256) void k_histW(const int* __restrict__ dstv,
    unsigned int* __restrict__ partial, int E, int Etot, int chunk,
    const float* __restrict__ W1, _Float16* __restrict__ W1t,
    const float* __restrict__ W2, _Float16* __restrict__ W2t)
{
  int b = blockIdx.x, t = threadIdx.x;
  if (b >= NBK){
    int b2 = b - NBK;
    if (b2 < 128){
      W1t[t*128 + b2] = (_Float16)W1[b2*256 + t];
    } else {
      for (int i=t; i<4096; i+=256){ int k=i&255, j=i>>8; W2t[j*256+k] = (_Float16)W2[k*16+j]; }
    }
    return;
  }
  __shared__ unsigned int cnt[NWH];         // 50 KB -> 2 blocks/CU
  int c = b >> 1, half = b & 1, lo = half*HBINS;
  for (int i=t; i<NWH; i+=256) cnt[i] = 0u;
  __syncthreads();
  int e0 = c*chunk, e1 = e0+chunk; if (e1 > Etot) e1 = Etot;
  int e = e0 + t;
  for (; e + 768 < e1; e += 1024){
    int ea=e, eb=e+256, ec=e+512, ed=e+768;
    int d0 = (ea<E)?dstv[ea]:(ea-E);
    int d1 = (eb<E)?dstv[eb]:(eb-E);
    int d2 = (ec<E)?dstv[ec]:(ec-E);
    int d3 = (ed<E)?dstv[ed]:(ed-E);
    int r0=d0-lo, r1=d1-lo, r2=d2-lo, r3=d3-lo;
    if (r0>=0 && r0<HBINS) atomicAdd(&cnt[r0>>1], (r0&1)?65536u:1u);
    if (r1>=0 && r1<HBINS) atomicAdd(&cnt[r1>>1], (r1&1)?65536u:1u);
    if (r2>=0 && r2<HBINS) atomicAdd(&cnt[r2>>1], (r2&1)?65536u:1u);
    if (r3>=0 && r3<HBINS) atomicAdd(&cnt[r3>>1], (r3&1)?65536u:1u);
  }
  for (; e < e1; e += 256){
    int d = (e<E)?dstv[e]:(e-E);
    int r = d - lo;
    if (r>=0 && r<HBINS) atomicAdd(&cnt[r>>1], (r&1)?65536u:1u);
  }
  __syncthreads();
  unsigned int* dp = partial + (size_t)c*HBINS + (size_t)half*NWH;
  for (int i=t; i<NWH; i+=256) dp[i] = cnt[i];
}

// ---------------- K2: scanAB (blocks 0..SB-1) + GEMM1 tiles (blocks SB..) ----------------
__global__ __launch_bounds__(256) void k_g1scan(const float* __restrict__ x,
    const _Float16* __restrict__ W1t, const float* __restrict__ as1,
    const float* __restrict__ ad1, _Float16* __restrict__ h1,
    float* __restrict__ a_src1, float* __restrict__ a_dst1,
    unsigned long long* __restrict__ partial, int* __restrict__ rowptr,
    int* __restrict__ bsum, int N, int SB)
{
  __shared__ char smem[33792];
  int t = threadIdx.x;
  int b = blockIdx.x;

  if (b < SB){
    int* lds = (int*)smem;
    int base = b*1024 + t*4;
    int r0=0, r1=0, r2=0, r3=0;
    if (base < N){
      unsigned long long* P = partial + (base >> 2);
      #pragma unroll 8
      for (int cc=0; cc<NC; ++cc){
        unsigned long long v = P[(size_t)cc*12500];
        unsigned long long pref =  (unsigned long long)(r0 & 0xffff)
          | ((unsigned long long)(r1 & 0xffff) << 16)
          | ((unsigned long long)(r2 & 0xffff) << 32)
          | ((unsigned long long)(r3 & 0xffff) << 48);
        P[(size_t)cc*12500] = pref;
        r0 += (int)( v        & 0xffff);
        r1 += (int)((v >> 16) & 0xffff);
        r2 += (int)((v >> 32) & 0xffff);
        r3 += (int)((v >> 48) & 0xffff);
      }
    }
    int tot = r0+r1+r2+r3;
    lds[t] = tot; __syncthreads();
    for (int off=1; off<256; off<<=1){
      int add = (t>=off)?lds[t-off]:0;
      __syncthreads();
      lds[t] += add;
      __syncthreads();
    }
    int excl = lds[t] - tot;
    if (t==255) bsum[b] = lds[t];
    int run = excl;
    if (base+0<N){ rowptr[base+0]=run; run+=r0; }
    if (base+1<N){ rowptr[base+1]=run; run+=r1; }
    if (base+2<N){ rowptr[base+2]=run; run+=r2; }
    if (base+3<N){ rowptr[base+3]=run; }
    return;
  }

  // ---- GEMM1 (MFMA): h1 = x @ W1 -> fp16, + a_src1/a_dst1 ----
  _Float16* As = (_Float16*)smem;           // [64 rows][136 halves] (272 B stride)
  int n0 = (b - SB)*64;

  #pragma unroll
  for (int it=0; it<8; ++it){
    int c = it*256 + t;
    int row = c >> 5;
    int c4  = c & 31;
    int gr = n0 + row; if (gr > N-1) gr = N-1;
    float4 v = *(const float4*)(x + (size_t)gr*128 + c4*4);
    _Float16* dp = As + row*136 + c4*4;
    dp[0]=(_Float16)v.x; dp[1]=(_Float16)v.y; dp[2]=(_Float16)v.z; dp[3]=(_Float16)v.w;
  }
  __syncthreads();

  int wv = t>>6, lane = t&63;
  int m = lane&15, q = lane>>4;
  int r0w = wv*16;

  f16x8 afr[4];
  #pragma unroll
  for (int ks=0; ks<4; ++ks)
    afr[ks] = *(const f16x8*)((const char*)As + (r0w+m)*272 + ks*64 + q*16);

  f32x4 acc[16];
  #pragma unroll
  for (int ct=0; ct<16; ++ct) acc[ct] = (f32x4){0.f,0.f,0.f,0.f};

  const char* bbase = (const char*)W1t;
  #pragma unroll
  for (int ct=0; ct<16; ++ct){
    const char* bp = bbase + (ct*16 + m)*256 + q*16;
    f16x8 b0 = *(const f16x8*)(bp);
    f16x8 b1 = *(const f16x8*)(bp+64);
    f16x8 b2 = *(const f16x8*)(bp+128);
    f16x8 b3 = *(const f16x8*)(bp+192);
    acc[ct] = __builtin_amdgcn_mfma_f32_16x16x32_f16(afr[0], b0, acc[ct],0,0,0);
    acc[ct] = __builtin_amdgcn_mfma_f32_16x16x32_f16(afr[1], b1, acc[ct],0,0,0);
    acc[ct] = __builtin_amdgcn_mfma_f32_16x16x32_f16(afr[2], b2, acc[ct],0,0,0);
    acc[ct] = __builtin_amdgcn_mfma_f32_16x16x32_f16(afr[3], b3, acc[ct],0,0,0);
  }
  __syncthreads();

  _Float16* Hs = (_Float16*)smem;           // [64][264] halves, 528B stride
  #pragma unroll
  for (int ct=0; ct<16; ++ct){
    #pragma unroll
    for (int r=0; r<4; ++r)
      Hs[(size_t)(r0w + q*4 + r)*264 + ct*16 + m] = (_Float16)acc[ct][r];
  }
  __syncthreads();

  for (int r=0; r<16; ++r){
    int grow = n0 + r0w + r;
    if (grow < N){
      uint2 v = *(const uint2*)((const char*)Hs + (size_t)(r0w+r)*528 + lane*8);
      *(uint2*)((char*)h1 + (size_t)grow*512 + lane*8) = v;
    }
  }

  #pragma unroll
  for (int p=t; p<512; p+=256){
    int row = p>>3, hd = p&7;
    int grow = n0 + row;
    if (grow < N){
      const _Float16* hr = Hs + (size_t)row*264 + hd*32;
      float sa=0.f, sd=0.f;
      #pragma unroll
      for (int c=0; c<32; ++c){
        float hv = (float)hr[c];
        sa += hv * as1[hd*32+c];
        sd += hv * ad1[hd*32+c];
      }
      a_src1[(size_t)grow*8+hd] = sa;
      a_dst1[(size_t)grow*8+hd] = sd;
    }
  }
}

// ---------------- K3: scatter (chunk x half, LDS u16 cursors) + rowfin finalize ----------------
__global__ __launch_bounds__(256) void k_scatter3(const int* __restrict__ srcv,
    const int* __restrict__ dstv, const int* __restrict__ rowptr,
    const unsigned short* __restrict__ pu, const int* __restrict__ bsum,
    int* __restrict__ csr_src, int* __restrict__ rowfin,
    int E, int Etot, int chunk, int SB, int N)
{
  __shared__ unsigned int cur[NWH];         // 50 KB -> 2 blocks/CU
  __shared__ int bpre[64];
  int b = blockIdx.x, t = threadIdx.x;
  int c = b >> 1, half = b & 1, lo = half*HBINS;
  for (int i=t; i<NWH; i+=256) cur[i] = 0u;
  if (t==0){ int run=0; for (int j=0;j<SB;++j){ bpre[j]=run; run+=bsum[j]; } }
  __syncthreads();

  if (b < SB){
    int pref = bpre[b];
    int i = b*1024 + t*4;
    if (i+0 < N) rowfin[i+0] = rowptr[i+0] + pref;
    if (i+1 < N) rowfin[i+1] = rowptr[i+1] + pref;
    if (i+2 < N) rowfin[i+2] = rowptr[i+2] + pref;
    if (i+3 < N) rowfin[i+3] = rowptr[i+3] + pref;
    if (b==0 && t==0) rowfin[N] = Etot;
  }

  const unsigned short* pb = pu + (size_t)c*NBINS;
  int e0 = c*chunk, e1 = e0+chunk; if (e1 > Etot) e1 = Etot;
  int e = e0 + t;
  for (; e + 768 < e1; e += 1024){
    int ea=e, eb=e+256, ec=e+512, ed=e+768;
    int d0,s0,d1,s1,d2,s2,d3,s3;
    if (ea<E){ d0=dstv[ea]; s0=srcv[ea]; } else { d0=ea-E; s0=d0; }
    if (eb<E){ d1=dstv[eb]; s1=srcv[eb]; } else { d1=eb-E; s1=d1; }
    if (ec<E){ d2=dstv[ec]; s2=srcv[ec]; } else { d2=ec-E; s2=d2; }
    if (ed<E){ d3=dstv[ed]; s3=srcv[ed]; } else { d3=ed-E; s3=d3; }
    int r0=d0-lo, r1=d1-lo, r2=d2-lo, r3=d3-lo;
    if (r0>=0 && r0<HBINS){
      int base0 = rowptr[d0] + bpre[d0>>10] + (int)pb[d0];
      unsigned int o0 = atomicAdd(&cur[r0>>1], (r0&1)?65536u:1u);
      csr_src[base0 + ((r0&1)?(int)(o0>>16):(int)(o0&0xffff))] = s0;
    }
    if (r1>=0 && r1<HBINS){
      int base1 = rowptr[d1] + bpre[d1>>10] + (int)pb[d1];
      unsigned int o1 = atomicAdd(&cur[r1>>1], (r1&1)?65536u:1u);
      csr_src[base1 + ((r1&1)?(int)(o1>>16):(int)(o1&0xffff))] = s1;
    }
    if (r2>=0 && r2<HBINS){
      int base2 = rowptr[d2] + bpre[d2>>10] + (int)pb[d2];
      unsigned int o2 = atomicAdd(&cur[r2>>1], (r2&1)?65536u:1u);
      csr_src[base2 + ((r2&1)?(int)(o2>>16):(int)(o2&0xffff))] = s2;
    }
    if (r3>=0 && r3<HBINS){
      int base3 = rowptr[d3] + bpre[d3>>10] + (int)pb[d3];
      unsigned int o3 = atomicAdd(&cur[r3>>1], (r3&1)?65536u:1u);
      csr_src[base3 + ((r3&1)?(int)(o3>>16):(int)(o3&0xffff))] = s3;
    }
  }
  for (; e < e1; e += 256){
    int d,s;
    if (e<E){ d=dstv[e]; s=srcv[e]; } else { d=e-E; s=d; }
    int r = d - lo;
    if (r>=0 && r<HBINS){
      int base = rowptr[d] + bpre[d>>10] + (int)pb[d];
      unsigned int o = atomicAdd(&cur[r>>1], (r&1)?65536u:1u);
      csr_src[base + ((r&1)?(int)(o>>16):(int)(o&0xffff))] = s;
    }
  }
}

// ---------------- K4: Layer-1 aggregation (wave/dst, x8/x4/x1; dst range [d0,d1)) ----------------
__global__ __launch_bounds__(256) void k_agg1(const __half* __restrict__ h1,
    const float* __restrict__ a_src1, const float* __restrict__ a_dst1,
    const int* __restrict__ rowfin, const int* __restrict__ csr_src,
    const float* __restrict__ bias1, _Float16* __restrict__ h2f, int d0, int d1)
{
  int wave = d0 + ((blockIdx.x*blockDim.x + threadIdx.x) >> 6);
  if (wave >= d1) return;
  int lane = threadIdx.x & 63;
  int head = lane >> 3;
  float ad = a_dst1[(size_t)wave*8 + head];
  int beg = rowfin[wave], end = rowfin[wave+1];
  float4 acc = make_float4(0.f,0.f,0.f,0.f);
  float wsum = 0.f;
  int i = beg;
  for (; i+8 <= end; i+=8){
    int s[8]; float e[8]; uint2 p[8];
    #pragma unroll
    for (int j=0;j<8;++j) s[j]=csr_src[i+j];
    #pragma unroll
    for (int j=0;j<8;++j){
      e[j]=a_src1[(size_t)s[j]*8+head];
      p[j]=*(const uint2*)((const char*)h1 + (size_t)s[j]*512 + lane*8);
    }
    #pragma unroll
    for (int j=0;j<8;++j){
      float w=__expf(lrelu(e[j]+ad));
      wsum += w;
      const __half2* qq=(const __half2*)&p[j];
      float2 f0=__half22float2(qq[0]), f1=__half22float2(qq[1]);
      acc.x += w*f0.x; acc.y += w*f0.y; acc.z += w*f1.x; acc.w += w*f1.y;
    }
  }
  for (; i+4 <= end; i+=4){
    int s[4]; float e[4]; uint2 p[4];
    #pragma unroll
    for (int j=0;j<4;++j) s[j]=csr_src[i+j];
    #pragma unroll
    for (int j=0;j<4;++j){
      e[j]=a_src1[(size_t)s[j]*8+head];
      p[j]=*(const uint2*)((const char*)h1 + (size_t)s[j]*512 + lane*8);
    }
    #pragma unroll
    for (int j=0;j<4;++j){
      float w=__expf(lrelu(e[j]+ad));
      wsum += w;
      const __half2* qq=(const __half2*)&p[j];
      float2 f0=__half22float2(qq[0]), f1=__half22float2(qq[1]);
      acc.x += w*f0.x; acc.y += w*f0.y; acc.z += w*f1.x; acc.w += w*f1.y;
    }
  }
  for (; i<end; ++i){
    int s = csr_src[i];
    float w = __expf(lrelu(a_src1[(size_t)s*8+head] + ad));
    wsum += w;
    uint2 p = *(const uint2*)((const char*)h1 + (size_t)s*512 + lane*8);
    const __half2* qq=(const __half2*)&p;
    float2 f0=__half22float2(qq[0]), f1=__half22float2(qq[1]);
    acc.x += w*f0.x; acc.y += w*f0.y; acc.z += w*f1.x; acc.w += w*f1.y;
  }
  float dinv = 1.f/(wsum + 1e-16f);
  const float4 bv = *(const float4*)(bias1 + lane*4);
  float4 o;
  o.x = acc.x*dinv + bv.x;
  o.y = acc.y*dinv + bv.y;
  o.z = acc.z*dinv + bv.z;
  o.w = acc.w*dinv + bv.w;
  o.x = o.x > 0.f ? o.x : __expf(o.x)-1.f;
  o.y = o.y > 0.f ? o.y : __expf(o.y)-1.f;
  o.z = o.z > 0.f ? o.z : __expf(o.z)-1.f;
  o.w = o.w > 0.f ? o.w : __expf(o.w)-1.f;
  f16x4 ov = { (_Float16)o.x, (_Float16)o.y, (_Float16)o.z, (_Float16)o.w };
  *(f16x4*)(h2f + (size_t)wave*256 + lane*4) = ov;
}

// ---------------- K5: GEMM2 (MFMA): hb(fp16) = h2f @ W2, + a_src2/a_dst2 ----------------
__global__ __launch_bounds__(256) void k_gemm2(const _Float16* __restrict__ h2f,
    const _Float16* __restrict__ W2t, const float* __restrict__ as2, const float* __restrict__ ad2,
    _Float16* __restrict__ hbh, float* __restrict__ a_src2, float* __restrict__ a_dst2, int N)
{
  int t = threadIdx.x, wv = t>>6, lane = t&63;
  int col = lane&15, q = lane>>4;
  int n0 = blockIdx.x*64 + wv*16;
  int am = n0 + col; if (am > N-1) am = N-1;

  const _Float16* arow = h2f + (size_t)am*256 + q*8;
  const _Float16* brow = W2t + (size_t)col*256 + q*8;
  f32x4 acc = (f32x4){0.f,0.f,0.f,0.f};
  #pragma unroll
  for (int ks=0; ks<8; ++ks){
    f16x8 a = *(const f16x8*)(arow + ks*32);
    f16x8 b = *(const f16x8*)(brow + ks*32);
    acc = __builtin_amdgcn_mfma_f32_16x16x32_f16(a, b, acc, 0,0,0);
  }

  float vs = as2[col], vd = ad2[col];
  #pragma unroll
  for (int r=0; r<4; ++r){
    int n = n0 + q*4 + r;
    float v = acc[r];
    float pa = v*vs, pd = v*vd;
    #pragma unroll
    for (int msk=8; msk>=1; msk>>=1){ pa += __shfl_xor(pa,msk); pd += __shfl_xor(pd,msk); }
    if (n < N){
      hbh[(size_t)n*16 + col] = (_Float16)v;
      if (col==0){ a_src2[n] = pa; a_dst2[n] = pd; }
    }
  }
}

// ---------------- K6: Layer-2 aggregation: wave per dst, 4 edge-groups x 16 ch ----------------
__global__ __launch_bounds__(256) void k_agg2(const __half* __restrict__ hbh,
    const float* __restrict__ a_src2, const float* __restrict__ a_dst2,
    const int* __restrict__ rowfin, const int* __restrict__ csr_src,
    const float* __restrict__ bias2, float* __restrict__ out, int N)
{
  int wave = (blockIdx.x*blockDim.x + threadIdx.x) >> 6;
  if (wave >= N) return;
  int lane = threadIdx.x & 63;
  int eg   = lane >> 4;
  int ch   = lane & 15;
  float ad = a_dst2[wave];
  int beg = rowfin[wave], end = rowfin[wave+1];
  float acc = 0.f, wsum = 0.f;
  int i = beg + eg;
  for (; i+4 < end; i+=8){
    int s0 = csr_src[i], s1 = csr_src[i+4];
    float e0 = a_src2[s0], e1 = a_src2[s1];
    float h0 = __half2float(hbh[(size_t)s0*16 + ch]);
    float h1v = __half2float(hbh[(size_t)s1*16 + ch]);
    float w0 = __expf(lrelu(e0 + ad)), w1 = __expf(lrelu(e1 + ad));
    wsum += w0 + w1;
    acc += w0*h0 + w1*h1v;
  }
  for (; i<end; i+=4){
    int s = csr_src[i];
    float w = __expf(lrelu(a_src2[s] + ad));
    wsum += w;
    acc += w * __half2float(hbh[(size_t)s*16 + ch]);
  }
  acc  += __shfl_xor(acc, 16);  acc  += __shfl_xor(acc, 32);
  wsum += __shfl_xor(wsum, 16); wsum += __shfl_xor(wsum, 32);
  if (eg == 0)
    out[(size_t)wave*16 + ch] = acc/(wsum + 1e-16f) + bias2[ch];
}

extern "C" void kernel_launch(void* const* d_in, const int* in_sizes, int n_in,
                              void* d_out, int out_size, void* d_ws, size_t ws_size,
                              hipStream_t stream)
{
  const float* x   = (const float*)d_in[0];
  const int*   ei  = (const int*)  d_in[1];
  const float* W1  = (const float*)d_in[2];
  const float* as1 = (const float*)d_in[3];
  const float* ad1 = (const float*)d_in[4];
  const float* b1  = (const float*)d_in[5];
  const float* W2  = (const float*)d_in[6];
  const float* as2 = (const float*)d_in[7];
  const float* ad2 = (const float*)d_in[8];
  const float* b2  = (const float*)d_in[9];
  float* out = (float*)d_out;

  const int N    = in_sizes[0] / 128;       // 50000
  const int E    = in_sizes[1] / 2;         // 800000
  const int Etot = E + N;
  const int* srcv = ei;
  const int* dstv = ei + E;
  const int chunk = (Etot + NC - 1) / NC;   // 6641 < 65536 (u16-field safe)
  const int SB    = (N + 1023) / 1024;      // 49 scan blocks
  const int TN    = (N + 63) / 64;          // 782 gemm1 tiles
  const int Nh    = N / 2;                  // 25000 (agg1 half split)

  char* p = (char*)d_ws;
  auto alloc = [&](size_t bytes)->void* {
    void* r = (void*)p;
    p += (bytes + 255) & ~((size_t)255);
    return r;
  };
  _Float16* h1   = (_Float16*)alloc((size_t)N*256*sizeof(_Float16));   // node-major [N][256]
  _Float16* W1t  = (_Float16*)alloc((size_t)256*128*sizeof(_Float16));
  _Float16* h2f  = (_Float16*)alloc((size_t)N*256*sizeof(_Float16));
  _Float16* W2t  = (_Float16*)alloc((size_t)16*256*sizeof(_Float16));
  _Float16* hbh  = (_Float16*)alloc((size_t)N*16*sizeof(_Float16));
  float* a_src1  = (float*)alloc((size_t)N*8*sizeof(float));
  float* a_dst1  = (float*)alloc((size_t)N*8*sizeof(float));
  float* a_src2  = (float*)alloc((size_t)N*sizeof(float));
  float* a_dst2  = (float*)alloc((size_t)N*sizeof(float));
  int*   rowptr  = (int*)alloc((size_t)(N+1)*sizeof(int));
  int*   rowfin  = (int*)alloc((size_t)(N+1)*sizeof(int));
  int*   bsum    = (int*)alloc(256*sizeof(int));
  unsigned int* partial = (unsigned int*)alloc((size_t)NC*HBINS*sizeof(unsigned int)); // u16[NC][50000]
  int*   csr_src = (int*)alloc((size_t)Etot*sizeof(int));

  // K1: histogram (chunk x half, 256 blocks) + weight prep
  k_histW<<<dim3(NBK+129), dim3(256), 0, stream>>>(dstv, partial, E, Etot, chunk,
                                                   W1, W1t, W2, W2t);
  // K2: scanAB (blocks 0..SB-1) + gemm1 (blocks SB..SB+TN-1)
  k_g1scan<<<dim3(SB + TN), dim3(256), 0, stream>>>(x, W1t, as1, ad1, h1,
      a_src1, a_dst1, (unsigned long long*)partial, rowptr, bsum, N, SB);
  // K3: scatter + rowfin finalize
  k_scatter3<<<dim3(NBK), dim3(256), 0, stream>>>(srcv, dstv, rowptr,
      (const unsigned short*)partial, bsum, csr_src, rowfin, E, Etot, chunk, SB, N);
  // K4a/K4b: agg1 halves (diagnostic split -- drops agg1 below mid-tier in top-5)
  k_agg1<<<dim3((Nh + 3)/4), dim3(256), 0, stream>>>((const __half*)h1, a_src1, a_dst1,
      rowfin, csr_src, b1, h2f, 0, Nh);
  k_agg1<<<dim3((N - Nh + 3)/4), dim3(256), 0, stream>>>((const __half*)h1, a_src1, a_dst1,
      rowfin, csr_src, b1, h2f, Nh, N);
  // K5: gemm2 (fp16 hb)
  k_gemm2<<<dim3((N + 63)/64), dim3(256), 0, stream>>>(h2f, W2t, as2, ad2, hbh, a_src2, a_dst2, N);
  // K6: agg2
  k_agg2<<<dim3((N + 3)/4), dim3(256), 0, stream>>>((const __half*)hbh, a_src2, a_dst2,
      rowfin, csr_src, b2, out, N);
}

// Round 16
// 269.376 us; speedup vs baseline: 1.1987x; 1.0152x over previous
//
#include <hip/hip_runtime.h>
#include <hip/hip_fp16.h>
#include <math.h>

// 2-layer GAT. N=50000, E=800000 (+N self loops), F=128, H=8, C=32, NCLS=16.
// R16: R15 diagnostic found k_g1scan = 59us with ALL pipes idle (MfmaUtil 2%,
// VALU 5.5%, 1TB/s) -- latency-bound straggler = the scan branch's 128-iter
// serial chunk loop (100KB-stride loads, ~700cyc each, compiler didn't
// pipeline). Fix: explicit 16-deep batched prefetch (8 batches of independent
// loads -> ~2.5us). agg1 back to single launch (split cost ~4us).
//   K1 histW | K2 scanAB+gemm1 | K3 scatter3+rowfin | K4 agg1 | K5 gemm2 | K6 agg2

#define NC    128          // edge chunks
#define NBK   256          // hist/scatter blocks = NC * 2 halves
#define NBINS 50000
#define HBINS 25000        // bins per half
#define NWH   12500        // packed u32 words per half (2 bins each)

typedef _Float16 f16x8 __attribute__((ext_vector_type(8)));
typedef _Float16 f16x4 __attribute__((ext_vector_type(4)));
typedef float    f32x4 __attribute__((ext_vector_type(4)));

__device__ __forceinline__ float lrelu(float v){ return v > 0.f ? v : 0.2f*v; }

// ---------------- K1: hist (packed u16, chunk x half) + weight prep ----------------
__global__ __launch_bounds__(256) void k_histW(const int* __restrict__ dstv,
    unsigned int* __restrict__ partial, int E, int Etot, int chunk,
    const float* __restrict__ W1, _Float16* __restrict__ W1t,
    const float* __restrict__ W2, _Float16* __restrict__ W2t)
{
  int b = blockIdx.x, t = threadIdx.x;
  if (b >= NBK){
    int b2 = b - NBK;
    if (b2 < 128){
      W1t[t*128 + b2] = (_Float16)W1[b2*256 + t];
    } else {
      for (int i=t; i<4096; i+=256){ int k=i&255, j=i>>8; W2t[j*256+k] = (_Float16)W2[k*16+j]; }
    }
    return;
  }
  __shared__ unsigned int cnt[NWH];         // 50 KB -> 2 blocks/CU
  int c = b >> 1, half = b & 1, lo = half*HBINS;
  for (int i=t; i<NWH; i+=256) cnt[i] = 0u;
  __syncthreads();
  int e0 = c*chunk, e1 = e0+chunk; if (e1 > Etot) e1 = Etot;
  int e = e0 + t;
  for (; e + 768 < e1; e += 1024){
    int ea=e, eb=e+256, ec=e+512, ed=e+768;
    int d0 = (ea<E)?dstv[ea]:(ea-E);
    int d1 = (eb<E)?dstv[eb]:(eb-E);
    int d2 = (ec<E)?dstv[ec]:(ec-E);
    int d3 = (ed<E)?dstv[ed]:(ed-E);
    int r0=d0-lo, r1=d1-lo, r2=d2-lo, r3=d3-lo;
    if (r0>=0 && r0<HBINS) atomicAdd(&cnt[r0>>1], (r0&1)?65536u:1u);
    if (r1>=0 && r1<HBINS) atomicAdd(&cnt[r1>>1], (r1&1)?65536u:1u);
    if (r2>=0 && r2<HBINS) atomicAdd(&cnt[r2>>1], (r2&1)?65536u:1u);
    if (r3>=0 && r3<HBINS) atomicAdd(&cnt[r3>>1], (r3&1)?65536u:1u);
  }
  for (; e < e1; e += 256){
    int d = (e<E)?dstv[e]:(e-E);
    int r = d - lo;
    if (r>=0 && r<HBINS) atomicAdd(&cnt[r>>1], (r&1)?65536u:1u);
  }
  __syncthreads();
  unsigned int* dp = partial + (size_t)c*HBINS + (size_t)half*NWH;
  for (int i=t; i<NWH; i+=256) dp[i] = cnt[i];
}

// ---------------- K2: scanAB (blocks 0..SB-1, batched prefetch) + GEMM1 tiles ----------------
__global__ __launch_bounds__(256) void k_g1scan(const float* __restrict__ x,
    const _Float16* __restrict__ W1t, const float* __restrict__ as1,
    const float* __restrict__ ad1, _Float16* __restrict__ h1,
    float* __restrict__ a_src1, float* __restrict__ a_dst1,
    unsigned long long* __restrict__ partial, int* __restrict__ rowptr,
    int* __restrict__ bsum, int N, int SB)
{
  __shared__ char smem[33792];
  int t = threadIdx.x;
  int b = blockIdx.x;

  if (b < SB){
    // ---- scanAB with explicit 16-deep load batching (breaks latency chain) ----
    int* lds = (int*)smem;
    int base = b*1024 + t*4;
    int r0=0, r1=0, r2=0, r3=0;
    if (base < N){
      unsigned long long* P = partial + (base >> 2);
      for (int cc0=0; cc0<NC; cc0+=16){
        unsigned long long v[16];
        #pragma unroll
        for (int j=0;j<16;++j) v[j] = P[(size_t)(cc0+j)*12500];   // 16 loads in flight
        #pragma unroll
        for (int j=0;j<16;++j){
          unsigned long long pref =  (unsigned long long)(r0 & 0xffff)
            | ((unsigned long long)(r1 & 0xffff) << 16)
            | ((unsigned long long)(r2 & 0xffff) << 32)
            | ((unsigned long long)(r3 & 0xffff) << 48);
          P[(size_t)(cc0+j)*12500] = pref;
          r0 += (int)( v[j]        & 0xffff);
          r1 += (int)((v[j] >> 16) & 0xffff);
          r2 += (int)((v[j] >> 32) & 0xffff);
          r3 += (int)((v[j] >> 48) & 0xffff);
        }
      }
    }
    int tot = r0+r1+r2+r3;
    lds[t] = tot; __syncthreads();
    for (int off=1; off<256; off<<=1){
      int add = (t>=off)?lds[t-off]:0;
      __syncthreads();
      lds[t] += add;
      __syncthreads();
    }
    int excl = lds[t] - tot;
    if (t==255) bsum[b] = lds[t];
    int run = excl;
    if (base+0<N){ rowptr[base+0]=run; run+=r0; }
    if (base+1<N){ rowptr[base+1]=run; run+=r1; }
    if (base+2<N){ rowptr[base+2]=run; run+=r2; }
    if (base+3<N){ rowptr[base+3]=run; }
    return;
  }

  // ---- GEMM1 (MFMA): h1 = x @ W1 -> fp16, + a_src1/a_dst1 ----
  _Float16* As = (_Float16*)smem;           // [64 rows][136 halves] (272 B stride)
  int n0 = (b - SB)*64;

  #pragma unroll
  for (int it=0; it<8; ++it){
    int c = it*256 + t;
    int row = c >> 5;
    int c4  = c & 31;
    int gr = n0 + row; if (gr > N-1) gr = N-1;
    float4 v = *(const float4*)(x + (size_t)gr*128 + c4*4);
    _Float16* dp = As + row*136 + c4*4;
    dp[0]=(_Float16)v.x; dp[1]=(_Float16)v.y; dp[2]=(_Float16)v.z; dp[3]=(_Float16)v.w;
  }
  __syncthreads();

  int wv = t>>6, lane = t&63;
  int m = lane&15, q = lane>>4;
  int r0w = wv*16;

  f16x8 afr[4];
  #pragma unroll
  for (int ks=0; ks<4; ++ks)
    afr[ks] = *(const f16x8*)((const char*)As + (r0w+m)*272 + ks*64 + q*16);

  f32x4 acc[16];
  #pragma unroll
  for (int ct=0; ct<16; ++ct) acc[ct] = (f32x4){0.f,0.f,0.f,0.f};

  const char* bbase = (const char*)W1t;
  #pragma unroll
  for (int ct=0; ct<16; ++ct){
    const char* bp = bbase + (ct*16 + m)*256 + q*16;
    f16x8 b0 = *(const f16x8*)(bp);
    f16x8 b1 = *(const f16x8*)(bp+64);
    f16x8 b2 = *(const f16x8*)(bp+128);
    f16x8 b3 = *(const f16x8*)(bp+192);
    acc[ct] = __builtin_amdgcn_mfma_f32_16x16x32_f16(afr[0], b0, acc[ct],0,0,0);
    acc[ct] = __builtin_amdgcn_mfma_f32_16x16x32_f16(afr[1], b1, acc[ct],0,0,0);
    acc[ct] = __builtin_amdgcn_mfma_f32_16x16x32_f16(afr[2], b2, acc[ct],0,0,0);
    acc[ct] = __builtin_amdgcn_mfma_f32_16x16x32_f16(afr[3], b3, acc[ct],0,0,0);
  }
  __syncthreads();

  _Float16* Hs = (_Float16*)smem;           // [64][264] halves, 528B stride
  #pragma unroll
  for (int ct=0; ct<16; ++ct){
    #pragma unroll
    for (int r=0; r<4; ++r)
      Hs[(size_t)(r0w + q*4 + r)*264 + ct*16 + m] = (_Float16)acc[ct][r];
  }
  __syncthreads();

  for (int r=0; r<16; ++r){
    int grow = n0 + r0w + r;
    if (grow < N){
      uint2 v = *(const uint2*)((const char*)Hs + (size_t)(r0w+r)*528 + lane*8);
      *(uint2*)((char*)h1 + (size_t)grow*512 + lane*8) = v;
    }
  }

  #pragma unroll
  for (int p=t; p<512; p+=256){
    int row = p>>3, hd = p&7;
    int grow = n0 + row;
    if (grow < N){
      const _Float16* hr = Hs + (size_t)row*264 + hd*32;
      float sa=0.f, sd=0.f;
      #pragma unroll
      for (int c=0; c<32; ++c){
        float hv = (float)hr[c];
        sa += hv * as1[hd*32+c];
        sd += hv * ad1[hd*32+c];
      }
      a_src1[(size_t)grow*8+hd] = sa;
      a_dst1[(size_t)grow*8+hd] = sd;
    }
  }
}

// ---------------- K3: scatter (chunk x half, LDS u16 cursors) + rowfin finalize ----------------
__global__ __launch_bounds__(256) void k_scatter3(const int* __restrict__ srcv,
    const int* __restrict__ dstv, const int* __restrict__ rowptr,
    const unsigned short* __restrict__ pu, const int* __restrict__ bsum,
    int* __restrict__ csr_src, int* __restrict__ rowfin,
    int E, int Etot, int chunk, int SB, int N)
{
  __shared__ unsigned int cur[NWH];         // 50 KB -> 2 blocks/CU
  __shared__ int bpre[64];
  int b = blockIdx.x, t = threadIdx.x;
  int c = b >> 1, half = b & 1, lo = half*HBINS;
  for (int i=t; i<NWH; i+=256) cur[i] = 0u;
  if (t==0){ int run=0; for (int j=0;j<SB;++j){ bpre[j]=run; run+=bsum[j]; } }
  __syncthreads();

  if (b < SB){
    int pref = bpre[b];
    int i = b*1024 + t*4;
    if (i+0 < N) rowfin[i+0] = rowptr[i+0] + pref;
    if (i+1 < N) rowfin[i+1] = rowptr[i+1] + pref;
    if (i+2 < N) rowfin[i+2] = rowptr[i+2] + pref;
    if (i+3 < N) rowfin[i+3] = rowptr[i+3] + pref;
    if (b==0 && t==0) rowfin[N] = Etot;
  }

  const unsigned short* pb = pu + (size_t)c*NBINS;
  int e0 = c*chunk, e1 = e0+chunk; if (e1 > Etot) e1 = Etot;
  int e = e0 + t;
  for (; e + 768 < e1; e += 1024){
    int ea=e, eb=e+256, ec=e+512, ed=e+768;
    int d0,s0,d1,s1,d2,s2,d3,s3;
    if (ea<E){ d0=dstv[ea]; s0=srcv[ea]; } else { d0=ea-E; s0=d0; }
    if (eb<E){ d1=dstv[eb]; s1=srcv[eb]; } else { d1=eb-E; s1=d1; }
    if (ec<E){ d2=dstv[ec]; s2=srcv[ec]; } else { d2=ec-E; s2=d2; }
    if (ed<E){ d3=dstv[ed]; s3=srcv[ed]; } else { d3=ed-E; s3=d3; }
    int r0=d0-lo, r1=d1-lo, r2=d2-lo, r3=d3-lo;
    if (r0>=0 && r0<HBINS){
      int base0 = rowptr[d0] + bpre[d0>>10] + (int)pb[d0];
      unsigned int o0 = atomicAdd(&cur[r0>>1], (r0&1)?65536u:1u);
      csr_src[base0 + ((r0&1)?(int)(o0>>16):(int)(o0&0xffff))] = s0;
    }
    if (r1>=0 && r1<HBINS){
      int base1 = rowptr[d1] + bpre[d1>>10] + (int)pb[d1];
      unsigned int o1 = atomicAdd(&cur[r1>>1], (r1&1)?65536u:1u);
      csr_src[base1 + ((r1&1)?(int)(o1>>16):(int)(o1&0xffff))] = s1;
    }
    if (r2>=0 && r2<HBINS){
      int base2 = rowptr[d2] + bpre[d2>>10] + (int)pb[d2];
      unsigned int o2 = atomicAdd(&cur[r2>>1], (r2&1)?65536u:1u);
      csr_src[base2 + ((r2&1)?(int)(o2>>16):(int)(o2&0xffff))] = s2;
    }
    if (r3>=0 && r3<HBINS){
      int base3 = rowptr[d3] + bpre[d3>>10] + (int)pb[d3];
      unsigned int o3 = atomicAdd(&cur[r3>>1], (r3&1)?65536u:1u);
      csr_src[base3 + ((r3&1)?(int)(o3>>16):(int)(o3&0xffff))] = s3;
    }
  }
  for (; e < e1; e += 256){
    int d,s;
    if (e<E){ d=dstv[e]; s=srcv[e]; } else { d=e-E; s=d; }
    int r = d - lo;
    if (r>=0 && r<HBINS){
      int base = rowptr[d] + bpre[d>>10] + (int)pb[d];
      unsigned int o = atomicAdd(&cur[r>>1], (r&1)?65536u:1u);
      csr_src[base + ((r&1)?(int)(o>>16):(int)(o&0xffff))] = s;
    }
  }
}

// ---------------- K4: Layer-1 aggregation (wave/dst, x8/x4/x1) ----------------
__global__ __launch_bounds__(256) void k_agg1(const __half* __restrict__ h1,
    const float* __restrict__ a_src1, const float* __restrict__ a_dst1,
    const int* __restrict__ rowfin, const int* __restrict__ csr_src,
    const float* __restrict__ bias1, _Float16* __restrict__ h2f, int N)
{
  int wave = (blockIdx.x*blockDim.x + threadIdx.x) >> 6;
  if (wave >= N) return;
  int lane = threadIdx.x & 63;
  int head = lane >> 3;
  float ad = a_dst1[(size_t)wave*8 + head];
  int beg = rowfin[wave], end = rowfin[wave+1];
  float4 acc = make_float4(0.f,0.f,0.f,0.f);
  float wsum = 0.f;
  int i = beg;
  for (; i+8 <= end; i+=8){
    int s[8]; float e[8]; uint2 p[8];
    #pragma unroll
    for (int j=0;j<8;++j) s[j]=csr_src[i+j];
    #pragma unroll
    for (int j=0;j<8;++j){
      e[j]=a_src1[(size_t)s[j]*8+head];
      p[j]=*(const uint2*)((const char*)h1 + (size_t)s[j]*512 + lane*8);
    }
    #pragma unroll
    for (int j=0;j<8;++j){
      float w=__expf(lrelu(e[j]+ad));
      wsum += w;
      const __half2* qq=(const __half2*)&p[j];
      float2 f0=__half22float2(qq[0]), f1=__half22float2(qq[1]);
      acc.x += w*f0.x; acc.y += w*f0.y; acc.z += w*f1.x; acc.w += w*f1.y;
    }
  }
  for (; i+4 <= end; i+=4){
    int s[4]; float e[4]; uint2 p[4];
    #pragma unroll
    for (int j=0;j<4;++j) s[j]=csr_src[i+j];
    #pragma unroll
    for (int j=0;j<4;++j){
      e[j]=a_src1[(size_t)s[j]*8+head];
      p[j]=*(const uint2*)((const char*)h1 + (size_t)s[j]*512 + lane*8);
    }
    #pragma unroll
    for (int j=0;j<4;++j){
      float w=__expf(lrelu(e[j]+ad));
      wsum += w;
      const __half2* qq=(const __half2*)&p[j];
      float2 f0=__half22float2(qq[0]), f1=__half22float2(qq[1]);
      acc.x += w*f0.x; acc.y += w*f0.y; acc.z += w*f1.x; acc.w += w*f1.y;
    }
  }
  for (; i<end; ++i){
    int s = csr_src[i];
    float w = __expf(lrelu(a_src1[(size_t)s*8+head] + ad));
    wsum += w;
    uint2 p = *(const uint2*)((const char*)h1 + (size_t)s*512 + lane*8);
    const __half2* qq=(const __half2*)&p;
    float2 f0=__half22float2(qq[0]), f1=__half22float2(qq[1]);
    acc.x += w*f0.x; acc.y += w*f0.y; acc.z += w*f1.x; acc.w += w*f1.y;
  }
  float dinv = 1.f/(wsum + 1e-16f);
  const float4 bv = *(const float4*)(bias1 + lane*4);
  float4 o;
  o.x = acc.x*dinv + bv.x;
  o.y = acc.y*dinv + bv.y;
  o.z = acc.z*dinv + bv.z;
  o.w = acc.w*dinv + bv.w;
  o.x = o.x > 0.f ? o.x : __expf(o.x)-1.f;
  o.y = o.y > 0.f ? o.y : __expf(o.y)-1.f;
  o.z = o.z > 0.f ? o.z : __expf(o.z)-1.f;
  o.w = o.w > 0.f ? o.w : __expf(o.w)-1.f;
  f16x4 ov = { (_Float16)o.x, (_Float16)o.y, (_Float16)o.z, (_Float16)o.w };
  *(f16x4*)(h2f + (size_t)wave*256 + lane*4) = ov;
}

// ---------------- K5: GEMM2 (MFMA): hb(fp16) = h2f @ W2, + a_src2/a_dst2 ----------------
__global__ __launch_bounds__(256) void k_gemm2(const _Float16* __restrict__ h2f,
    const _Float16* __restrict__ W2t, const float* __restrict__ as2, const float* __restrict__ ad2,
    _Float16* __restrict__ hbh, float* __restrict__ a_src2, float* __restrict__ a_dst2, int N)
{
  int t = threadIdx.x, wv = t>>6, lane = t&63;
  int col = lane&15, q = lane>>4;
  int n0 = blockIdx.x*64 + wv*16;
  int am = n0 + col; if (am > N-1) am = N-1;

  const _Float16* arow = h2f + (size_t)am*256 + q*8;
  const _Float16* brow = W2t + (size_t)col*256 + q*8;
  f32x4 acc = (f32x4){0.f,0.f,0.f,0.f};
  #pragma unroll
  for (int ks=0; ks<8; ++ks){
    f16x8 a = *(const f16x8*)(arow + ks*32);
    f16x8 b = *(const f16x8*)(brow + ks*32);
    acc = __builtin_amdgcn_mfma_f32_16x16x32_f16(a, b, acc, 0,0,0);
  }

  float vs = as2[col], vd = ad2[col];
  #pragma unroll
  for (int r=0; r<4; ++r){
    int n = n0 + q*4 + r;
    float v = acc[r];
    float pa = v*vs, pd = v*vd;
    #pragma unroll
    for (int msk=8; msk>=1; msk>>=1){ pa += __shfl_xor(pa,msk); pd += __shfl_xor(pd,msk); }
    if (n < N){
      hbh[(size_t)n*16 + col] = (_Float16)v;
      if (col==0){ a_src2[n] = pa; a_dst2[n] = pd; }
    }
  }
}

// ---------------- K6: Layer-2 aggregation: wave per dst, 4 edge-groups x 16 ch ----------------
__global__ __launch_bounds__(256) void k_agg2(const __half* __restrict__ hbh,
    const float* __restrict__ a_src2, const float* __restrict__ a_dst2,
    const int* __restrict__ rowfin, const int* __restrict__ csr_src,
    const float* __restrict__ bias2, float* __restrict__ out, int N)
{
  int wave = (blockIdx.x*blockDim.x + threadIdx.x) >> 6;
  if (wave >= N) return;
  int lane = threadIdx.x & 63;
  int eg   = lane >> 4;
  int ch   = lane & 15;
  float ad = a_dst2[wave];
  int beg = rowfin[wave], end = rowfin[wave+1];
  float acc = 0.f, wsum = 0.f;
  int i = beg + eg;
  for (; i+4 < end; i+=8){
    int s0 = csr_src[i], s1 = csr_src[i+4];
    float e0 = a_src2[s0], e1 = a_src2[s1];
    float h0 = __half2float(hbh[(size_t)s0*16 + ch]);
    float h1v = __half2float(hbh[(size_t)s1*16 + ch]);
    float w0 = __expf(lrelu(e0 + ad)), w1 = __expf(lrelu(e1 + ad));
    wsum += w0 + w1;
    acc += w0*h0 + w1*h1v;
  }
  for (; i<end; i+=4){
    int s = csr_src[i];
    float w = __expf(lrelu(a_src2[s] + ad));
    wsum += w;
    acc += w * __half2float(hbh[(size_t)s*16 + ch]);
  }
  acc  += __shfl_xor(acc, 16);  acc  += __shfl_xor(acc, 32);
  wsum += __shfl_xor(wsum, 16); wsum += __shfl_xor(wsum, 32);
  if (eg == 0)
    out[(size_t)wave*16 + ch] = acc/(wsum + 1e-16f) + bias2[ch];
}

extern "C" void kernel_launch(void* const* d_in, const int* in_sizes, int n_in,
                              void* d_out, int out_size, void* d_ws, size_t ws_size,
                              hipStream_t stream)
{
  const float* x   = (const float*)d_in[0];
  const int*   ei  = (const int*)  d_in[1];
  const float* W1  = (const float*)d_in[2];
  const float* as1 = (const float*)d_in[3];
  const float* ad1 = (const float*)d_in[4];
  const float* b1  = (const float*)d_in[5];
  const float* W2  = (const float*)d_in[6];
  const float* as2 = (const float*)d_in[7];
  const float* ad2 = (const float*)d_in[8];
  const float* b2  = (const float*)d_in[9];
  float* out = (float*)d_out;

  const int N    = in_sizes[0] / 128;       // 50000
  const int E    = in_sizes[1] / 2;         // 800000
  const int Etot = E + N;
  const int* srcv = ei;
  const int* dstv = ei + E;
  const int chunk = (Etot + NC - 1) / NC;   // 6641 < 65536 (u16-field safe)
  const int SB    = (N + 1023) / 1024;      // 49 scan blocks
  const int TN    = (N + 63) / 64;          // 782 gemm1 tiles

  char* p = (char*)d_ws;
  auto alloc = [&](size_t bytes)->void* {
    void* r = (void*)p;
    p += (bytes + 255) & ~((size_t)255);
    return r;
  };
  _Float16* h1   = (_Float16*)alloc((size_t)N*256*sizeof(_Float16));   // node-major [N][256]
  _Float16* W1t  = (_Float16*)alloc((size_t)256*128*sizeof(_Float16));
  _Float16* h2f  = (_Float16*)alloc((size_t)N*256*sizeof(_Float16));
  _Float16* W2t  = (_Float16*)alloc((size_t)16*256*sizeof(_Float16));
  _Float16* hbh  = (_Float16*)alloc((size_t)N*16*sizeof(_Float16));
  float* a_src1  = (float*)alloc((size_t)N*8*sizeof(float));
  float* a_dst1  = (float*)alloc((size_t)N*8*sizeof(float));
  float* a_src2  = (float*)alloc((size_t)N*sizeof(float));
  float* a_dst2  = (float*)alloc((size_t)N*sizeof(float));
  int*   rowptr  = (int*)alloc((size_t)(N+1)*sizeof(int));
  int*   rowfin  = (int*)alloc((size_t)(N+1)*sizeof(int));
  int*   bsum    = (int*)alloc(256*sizeof(int));
  unsigned int* partial = (unsigned int*)alloc((size_t)NC*HBINS*sizeof(unsigned int)); // u16[NC][50000]
  int*   csr_src = (int*)alloc((size_t)Etot*sizeof(int));

  // K1: histogram (chunk x half, 256 blocks) + weight prep
  k_histW<<<dim3(NBK+129), dim3(256), 0, stream>>>(dstv, partial, E, Etot, chunk,
                                                   W1, W1t, W2, W2t);
  // K2: scanAB (batched prefetch; blocks 0..SB-1) + gemm1 (blocks SB..SB+TN-1)
  k_g1scan<<<dim3(SB + TN), dim3(256), 0, stream>>>(x, W1t, as1, ad1, h1,
      a_src1, a_dst1, (unsigned long long*)partial, rowptr, bsum, N, SB);
  // K3: scatter + rowfin finalize
  k_scatter3<<<dim3(NBK), dim3(256), 0, stream>>>(srcv, dstv, rowptr,
      (const unsigned short*)partial, bsum, csr_src, rowfin, E, Etot, chunk, SB, N);
  // K4: agg1 (single launch)
  k_agg1<<<dim3((N + 3)/4), dim3(256), 0, stream>>>((const __half*)h1, a_src1, a_dst1,
      rowfin, csr_src, b1, h2f, N);
  // K5: gemm2 (fp16 hb)
  k_gemm2<<<dim3((N + 63)/64), dim3(256), 0, stream>>>(h2f, W2t, as2, ad2, hbh, a_src2, a_dst2, N);
  // K6: agg2
  k_agg2<<<dim3((N + 3)/4), dim3(256), 0, stream>>>((const __half*)hbh, a_src2, a_dst2,
      rowfin, csr_src, b2, out, N);
}